// Round 1
// baseline (16610.732 us; speedup 1.0000x reference)
//
#include <hip/hip_runtime.h>
#include <cstdint>
#include <cstddef>

// ---------------- helpers ----------------

__device__ __forceinline__ float sigmoidf_(float x) {
    return 1.0f / (1.0f + __expf(-x));
}

template<int OUT>
__device__ __forceinline__ void load_bias(const float* __restrict__ b, float* __restrict__ acc) {
#pragma unroll
    for (int j = 0; j < OUT; ++j) acc[j] = b[j];
}

template<int OUT>
__device__ __forceinline__ void relu_v(float* __restrict__ acc) {
#pragma unroll
    for (int j = 0; j < OUT; ++j) acc[j] = fmaxf(acc[j], 0.0f);
}

// acc[OUT] += x[IN] @ W[IN,OUT]  (W row-major, wave-uniform address -> scalar loads)
template<int IN, int OUT>
__device__ __forceinline__ void mm_acc(const float* __restrict__ x,
                                       const float* __restrict__ W,
                                       float* __restrict__ acc) {
#pragma unroll 4
    for (int k = 0; k < IN; ++k) {
        const float v = x[k];
#pragma unroll
        for (int j = 0; j < OUT; ++j) acc[j] = fmaf(v, W[k * OUT + j], acc[j]);
    }
}

// vectorized row gather (row must be 16B aligned; WIDTH % 4 == 0)
template<int WIDTH>
__device__ __forceinline__ void load_row(const float* __restrict__ p, float* __restrict__ x) {
#pragma unroll
    for (int k4 = 0; k4 < WIDTH / 4; ++k4) {
        float4 v = reinterpret_cast<const float4*>(p)[k4];
        x[k4 * 4 + 0] = v.x; x[k4 * 4 + 1] = v.y;
        x[k4 * 4 + 2] = v.z; x[k4 * 4 + 3] = v.w;
    }
}

// edge encoder: rbf(16) + raw(2) -> 4 -> 8 (relu after each)
__device__ __forceinline__ void enc_edge(int orig,
                                         const float* __restrict__ dist,
                                         const float* __restrict__ eraw,
                                         const float* __restrict__ We1, const float* __restrict__ be1,
                                         const float* __restrict__ We2, const float* __restrict__ be2,
                                         float* __restrict__ out8) {
    float x[18];
    const float d = dist[orig];
#pragma unroll
    for (int i = 0; i < 16; ++i) {
        const float c = (float)i * (20.0f / 15.0f);
        const float t = d - c;
        x[i] = __expf(-t * t);
    }
    x[16] = eraw[(size_t)orig * 2 + 0];
    x[17] = eraw[(size_t)orig * 2 + 1];
    float h[4];
    load_bias<4>(be1, h);
    mm_acc<18, 4>(x, We1, h);
    relu_v<4>(h);
    load_bias<8>(be2, out8);
    mm_acc<4, 8>(h, We2, out8);
    relu_v<8>(out8);
}

// ---------------- kernels ----------------

__global__ void __launch_bounds__(256) node_enc_kernel(
    const float* __restrict__ node_raw, const int* __restrict__ residues,
    const float* __restrict__ emb,
    const float* __restrict__ Wn1, const float* __restrict__ bn1,
    const float* __restrict__ Wn2, const float* __restrict__ bn2,
    float* __restrict__ nf0, int N)
{
    const int n = blockIdx.x * blockDim.x + threadIdx.x;
    if (n >= N) return;
    float h[8];
    load_bias<8>(bn1, h);
    // emb part: rows 0..31 of Wn1
    {
        const float* er = emb + (size_t)residues[n] * 32;
        float x[32];
        load_row<32>(er, x);
        mm_acc<32, 8>(x, Wn1, h);
    }
    // raw part: rows 32..82 of Wn1
    {
        const float* nr = node_raw + (size_t)n * 51;
#pragma unroll 4
        for (int k = 0; k < 51; ++k) {
            const float v = nr[k];
#pragma unroll
            for (int j = 0; j < 8; ++j) h[j] = fmaf(v, Wn1[(32 + k) * 8 + j], h[j]);
        }
    }
    relu_v<8>(h);
    float o[16];
    load_bias<16>(bn2, o);
    mm_acc<8, 16>(h, Wn2, o);
    relu_v<16>(o);
    float* dst = nf0 + (size_t)n * 16;
#pragma unroll
    for (int j = 0; j < 16; ++j) dst[j] = o[j];
}

__global__ void __launch_bounds__(256) deg_kernel(
    const int* __restrict__ senders, const int* __restrict__ receivers,
    float* __restrict__ deg, int E)
{
    const int e = blockIdx.x * blockDim.x + threadIdx.x;
    if (e >= E) return;
    atomicAdd(&deg[receivers[e]], 1.0f);  // rcv for first E edges
    atomicAdd(&deg[senders[e]], 1.0f);    // rcv for mirrored E edges
}

// Edge transform for layer LAYER (recomputes the chain from the encoder).
// Scatters ef_LAYER into agg[r * OE_LAYER + j] with atomics.
template<int LAYER>
__global__ void __launch_bounds__(256) edge_kernel(
    const float* __restrict__ dist, const float* __restrict__ eraw,
    const int* __restrict__ senders, const int* __restrict__ receivers,
    const float* __restrict__ nf0, const float* __restrict__ nf1, const float* __restrict__ nf2,
    const float* __restrict__ eWe1, const float* __restrict__ ebe1,
    const float* __restrict__ eWe2, const float* __restrict__ ebe2,
    const float* __restrict__ We0, const float* __restrict__ Ws0, const float* __restrict__ b0,
    const float* __restrict__ We1, const float* __restrict__ Ws1, const float* __restrict__ b1,
    const float* __restrict__ We2, const float* __restrict__ Ws2, const float* __restrict__ b2,
    float* __restrict__ agg, int E, int E2)
{
    const int e = blockIdx.x * blockDim.x + threadIdx.x;
    if (e >= E2) return;
    const int orig = (e < E) ? e : e - E;
    const int s = (e < E) ? senders[orig] : receivers[orig];
    const int r = (e < E) ? receivers[orig] : senders[orig];

    float enc[8];
    enc_edge(orig, dist, eraw, eWe1, ebe1, eWe2, ebe2, enc);

    // layer 0: ef0 = relu(enc @ We0 + nf0[s] @ Ws0 + b0)   [16]
    float a0[16];
    load_bias<16>(b0, a0);
    mm_acc<8, 16>(enc, We0, a0);
    {
        float x[16];
        load_row<16>(nf0 + (size_t)s * 16, x);
        mm_acc<16, 16>(x, Ws0, a0);
    }
    relu_v<16>(a0);

    if constexpr (LAYER == 0) {
        float* dst = agg + (size_t)r * 16;
#pragma unroll
        for (int j = 0; j < 16; ++j) atomicAdd(dst + j, a0[j]);
    } else {
        // layer 1: ef1 = relu(ef0 @ We1 + nf1[s] @ Ws1 + b1)  [32]
        float a1[32];
        load_bias<32>(b1, a1);
        mm_acc<16, 32>(a0, We1, a1);
        {
            float x[32];
            load_row<32>(nf1 + (size_t)s * 32, x);
            mm_acc<32, 32>(x, Ws1, a1);
        }
        relu_v<32>(a1);

        if constexpr (LAYER == 1) {
            float* dst = agg + (size_t)r * 32;
#pragma unroll
            for (int j = 0; j < 32; ++j) atomicAdd(dst + j, a1[j]);
        } else {
            // layer 2: ef2 = relu(ef1 @ We2 + nf2[s] @ Ws2 + b2)  [64]
            float a2[64];
            load_bias<64>(b2, a2);
            mm_acc<32, 64>(a1, We2, a2);
            {
                const float* xr = nf2 + (size_t)s * 64;
#pragma unroll 2
                for (int k4 = 0; k4 < 16; ++k4) {
                    float4 v = reinterpret_cast<const float4*>(xr)[k4];
                    const float vv[4] = {v.x, v.y, v.z, v.w};
#pragma unroll
                    for (int u = 0; u < 4; ++u) {
                        const float val = vv[u];
                        const int k = k4 * 4 + u;
#pragma unroll
                        for (int j = 0; j < 64; ++j) a2[j] = fmaf(val, Ws2[k * 64 + j], a2[j]);
                    }
                }
            }
            relu_v<64>(a2);
            float* dst = agg + (size_t)r * 64;
#pragma unroll
            for (int j = 0; j < 64; ++j) atomicAdd(dst + j, a2[j]);
        }
    }
}

// nf_new = relu(nf_in @ Wn + (agg/deg) @ Wi + bn); ON/32 threads per node
template<int INN, int OE, int ON>
__global__ void __launch_bounds__(256) node_layer_kernel(
    const float* __restrict__ nf_in, const float* __restrict__ agg, const float* __restrict__ deg,
    const float* __restrict__ Wn, const float* __restrict__ Wi, const float* __restrict__ bn,
    float* __restrict__ nf_out, int N)
{
    constexpr int TPN = (ON + 31) / 32;
    constexpr int JT = ON / TPN;    // 32 outputs per thread
    const int gid = blockIdx.x * blockDim.x + threadIdx.x;
    const int n = gid / TPN;
    const int c = gid % TPN;
    if (n >= N) return;
    const int jb = c * JT;

    float acc[JT];
#pragma unroll
    for (int j = 0; j < JT; ++j) acc[j] = bn[jb + j];

    {
        const float* x = nf_in + (size_t)n * INN;
#pragma unroll 4
        for (int k = 0; k < INN; ++k) {
            const float v = x[k];
#pragma unroll
            for (int j = 0; j < JT; ++j) acc[j] = fmaf(v, Wn[k * ON + jb + j], acc[j]);
        }
    }
    {
        const float inv = 1.0f / fmaxf(deg[n], 1.0f);
        const float* ag = agg + (size_t)n * OE;
#pragma unroll 4
        for (int k = 0; k < OE; ++k) {
            const float v = ag[k] * inv;
#pragma unroll
            for (int j = 0; j < JT; ++j) acc[j] = fmaf(v, Wi[k * ON + jb + j], acc[j]);
        }
    }
    float* o = nf_out + (size_t)n * ON + jb;
#pragma unroll
    for (int j = 0; j < JT; ++j) o[j] = fmaxf(acc[j], 0.0f);
}

__global__ void __launch_bounds__(256) readout_kernel(
    const float* __restrict__ nf3, const int* __restrict__ gidx,
    const float* __restrict__ roWn, const float* __restrict__ robn,
    float* __restrict__ node_out, float* __restrict__ gsum, float* __restrict__ gcnt, int N)
{
    const int n = blockIdx.x * blockDim.x + threadIdx.x;
    if (n >= N) return;
    const float* x = nf3 + (size_t)n * 128;
    const int g = gidx[n];
    float a0 = robn[0], a1 = robn[1];
    float* gs = gsum + (size_t)g * 128;
#pragma unroll 4
    for (int k = 0; k < 128; ++k) {
        const float v = x[k];
        a0 = fmaf(v, roWn[k * 2 + 0], a0);
        a1 = fmaf(v, roWn[k * 2 + 1], a1);
        atomicAdd(gs + k, v);
    }
    node_out[(size_t)n * 2 + 0] = sigmoidf_(a0);
    node_out[(size_t)n * 2 + 1] = sigmoidf_(a1);
    atomicAdd(gcnt + g, 1.0f);
}

__global__ void __launch_bounds__(256) glob_kernel(
    const float* __restrict__ gsum, const float* __restrict__ gcnt,
    const float* __restrict__ roWg, const float* __restrict__ robg,
    float* __restrict__ glob_out, int G)
{
    const int g = blockIdx.x * blockDim.x + threadIdx.x;
    if (g >= G) return;
    const float inv = 1.0f / fmaxf(gcnt[g], 1.0f);
    const float* gs = gsum + (size_t)g * 128;
    float a = robg[0];
#pragma unroll 4
    for (int k = 0; k < 128; ++k) a = fmaf(gs[k] * inv, roWg[k], a);
    glob_out[g] = sigmoidf_(a);
}

// ---------------- launch ----------------

extern "C" void kernel_launch(void* const* d_in, const int* in_sizes, int n_in,
                              void* d_out, int out_size, void* d_ws, size_t ws_size,
                              hipStream_t stream) {
    const float* node_raw  = (const float*)d_in[0];
    const float* edge_raw  = (const float*)d_in[1];
    const float* distances = (const float*)d_in[2];
    const int*   residues  = (const int*)d_in[3];
    const int*   senders   = (const int*)d_in[4];
    const int*   receivers = (const int*)d_in[5];
    const int*   gidx      = (const int*)d_in[6];
    const float* emb       = (const float*)d_in[7];
    const float* eWe1 = (const float*)d_in[8];  const float* ebe1 = (const float*)d_in[9];
    const float* eWe2 = (const float*)d_in[10]; const float* ebe2 = (const float*)d_in[11];
    const float* nWn1 = (const float*)d_in[12]; const float* nbn1 = (const float*)d_in[13];
    const float* nWn2 = (const float*)d_in[14]; const float* nbn2 = (const float*)d_in[15];
    const float* roWg = (const float*)d_in[16]; const float* robg = (const float*)d_in[17];
    const float* roWn = (const float*)d_in[18]; const float* robn = (const float*)d_in[19];
    const float* l0We = (const float*)d_in[20]; const float* l0Ws = (const float*)d_in[21];
    const float* l0be = (const float*)d_in[22]; const float* l0Wn = (const float*)d_in[23];
    const float* l0Wi = (const float*)d_in[24]; const float* l0bn = (const float*)d_in[25];
    const float* l1We = (const float*)d_in[26]; const float* l1Ws = (const float*)d_in[27];
    const float* l1be = (const float*)d_in[28]; const float* l1Wn = (const float*)d_in[29];
    const float* l1Wi = (const float*)d_in[30]; const float* l1bn = (const float*)d_in[31];
    const float* l2We = (const float*)d_in[32]; const float* l2Ws = (const float*)d_in[33];
    const float* l2be = (const float*)d_in[34]; const float* l2Wn = (const float*)d_in[35];
    const float* l2Wi = (const float*)d_in[36]; const float* l2bn = (const float*)d_in[37];

    const int N  = in_sizes[3];      // residues
    const int E  = in_sizes[2];      // distances
    const int G  = out_size - 2 * N; // node_out is N*2, glob is G*1
    const int E2 = 2 * E;

    float* ws = (float*)d_ws;
    size_t off = 0;
    float* nf0 = ws + off; off += (size_t)N * 16;
    float* nf1 = ws + off; off += (size_t)N * 32;
    float* nf2 = ws + off; off += (size_t)N * 64;
    float* nf3 = ws + off; off += (size_t)N * 128;
    float* agg = ws + off; off += (size_t)N * 64;
    float* deg = ws + off; off += (size_t)N;
    float* gsum = ws + off; off += (size_t)G * 128;
    float* gcnt = ws + off; off += (size_t)G;
    (void)ws_size; // required: ~122 MB

    const dim3 blk(256);
    const int nb_N  = (N + 255) / 256;
    const int nb_E  = (E + 255) / 256;
    const int nb_E2 = (E2 + 255) / 256;

    // zero accumulators (deg, gsum, gcnt are contiguous)
    hipMemsetAsync(deg, 0, sizeof(float) * ((size_t)N + (size_t)G * 128 + (size_t)G), stream);

    node_enc_kernel<<<nb_N, blk, 0, stream>>>(node_raw, residues, emb, nWn1, nbn1, nWn2, nbn2, nf0, N);
    deg_kernel<<<nb_E, blk, 0, stream>>>(senders, receivers, deg, E);

    // ---- layer 0 ----
    hipMemsetAsync(agg, 0, sizeof(float) * (size_t)N * 16, stream);
    edge_kernel<0><<<nb_E2, blk, 0, stream>>>(distances, edge_raw, senders, receivers,
        nf0, nf0, nf0, eWe1, ebe1, eWe2, ebe2,
        l0We, l0Ws, l0be, l1We, l1Ws, l1be, l2We, l2Ws, l2be, agg, E, E2);
    node_layer_kernel<16, 16, 32><<<nb_N, blk, 0, stream>>>(nf0, agg, deg, l0Wn, l0Wi, l0bn, nf1, N);

    // ---- layer 1 ----
    hipMemsetAsync(agg, 0, sizeof(float) * (size_t)N * 32, stream);
    edge_kernel<1><<<nb_E2, blk, 0, stream>>>(distances, edge_raw, senders, receivers,
        nf0, nf1, nf1, eWe1, ebe1, eWe2, ebe2,
        l0We, l0Ws, l0be, l1We, l1Ws, l1be, l2We, l2Ws, l2be, agg, E, E2);
    node_layer_kernel<32, 32, 64><<<(N * 2 + 255) / 256, blk, 0, stream>>>(nf1, agg, deg, l1Wn, l1Wi, l1bn, nf2, N);

    // ---- layer 2 ----
    hipMemsetAsync(agg, 0, sizeof(float) * (size_t)N * 64, stream);
    edge_kernel<2><<<nb_E2, blk, 0, stream>>>(distances, edge_raw, senders, receivers,
        nf0, nf1, nf2, eWe1, ebe1, eWe2, ebe2,
        l0We, l0Ws, l0be, l1We, l1Ws, l1be, l2We, l2Ws, l2be, agg, E, E2);
    node_layer_kernel<64, 64, 128><<<(N * 4 + 255) / 256, blk, 0, stream>>>(nf2, agg, deg, l2Wn, l2Wi, l2bn, nf3, N);

    // ---- readout ----
    readout_kernel<<<nb_N, blk, 0, stream>>>(nf3, gidx, roWn, robn, (float*)d_out, gsum, gcnt, N);
    glob_kernel<<<(G + 255) / 256, blk, 0, stream>>>(gsum, gcnt, roWg, robg, (float*)d_out + (size_t)2 * N, G);
}